// Round 5
// baseline (117.402 us; speedup 1.0000x reference)
//
#include <hip/hip_runtime.h>

// Problem constants (fixed by setup_inputs)
#define P_    1024          // H*W
#define KLEN  9
#define S_    8
#define N1_   36            // B1*KLEN
#define WP    34            // W + 2*pad
#define HH    32
#define WW    32
#define SPLIT 16            // split of the 128 (b0,c) pairs
#define BCPB  8             // (B0*C)/SPLIT pairs per block
#define THREADS 256
#define NBLK  (N1_ * SPLIT) // 576 blocks; __launch_bounds__(256,4) -> >=4 blk/CU -> 1024 capacity
#define LOG2E 1.4426950408889634f

// d_ws layout: 3 partial banks of N1_*SPLIT*8 floats, then control u32s.
#define PBANK    (N1_ * SPLIT * S_)       // 4608 floats
#define CTRL_OFF (3 * PBANK)              // float offset of control block
#define NCTRL    (2 + N1_)                // 2 barrier counters + 36 done counters

struct SharedBufs {
    float red[4][8];
    float vsh[8];
    int   last;
};

// Agent-scope (device) cache-bypassing accesses: per-XCD L2s are not coherent,
// so all cross-block data goes through these.
__device__ __forceinline__ float agent_loadf(const float* p) {
    return __hip_atomic_load(p, __ATOMIC_RELAXED, __HIP_MEMORY_SCOPE_AGENT);
}
__device__ __forceinline__ void agent_storef(float* p, float v) {
    __hip_atomic_store(p, v, __ATOMIC_RELAXED, __HIP_MEMORY_SCOPE_AGENT);
}

// Grid barrier: __syncthreads drains this block's stores (vmcnt 0), tid0 does a
// release-RMW arrival then acquire-spins until all NBLK blocks arrived.
// Counters zeroed by init_ctrl each call; monotone within a call (no reset races).
__device__ __forceinline__ void grid_barrier(unsigned* cnt) {
    __syncthreads();
    if (threadIdx.x == 0) {
        __hip_atomic_fetch_add(cnt, 1u, __ATOMIC_ACQ_REL, __HIP_MEMORY_SCOPE_AGENT);
        while (__hip_atomic_load(cnt, __ATOMIC_ACQUIRE, __HIP_MEMORY_SCOPE_AGENT)
               < (unsigned)NBLK)
            __builtin_amdgcn_s_sleep(8);
    }
    __syncthreads();
}

// Block-reduce acc[8] across 256 threads; store partial to out[slot*8+s] (agent scope).
__device__ __forceinline__ void block_reduce_store(SharedBufs& sh, float acc[8],
                                                   int slot, float* __restrict__ out) {
    int tid = threadIdx.x;
    int lane = tid & 63, wid = tid >> 6;
#pragma unroll
    for (int s = 0; s < 8; ++s) {
        float v = acc[s];
#pragma unroll
        for (int off = 32; off >= 1; off >>= 1) v += __shfl_down(v, off, 64);
        if (lane == 0) sh.red[wid][s] = v;
    }
    __syncthreads();
    if (tid < 8) {
        float t = sh.red[0][tid] + sh.red[1][tid] + sh.red[2][tid] + sh.red[3][tid];
        agent_storef(&out[slot * 8 + tid], t);
    }
}

// vp[8] = squash(scale * sum_i part[(n1*16+i)*8+s]); staged through LDS.
__device__ __forceinline__ void load_squash(SharedBufs& sh, const float* __restrict__ part,
                                            int n1, float scale, float vp[8]) {
    int tid = threadIdx.x;
    if (tid < 8) {
        float v = 0.f;
#pragma unroll
        for (int i = 0; i < SPLIT; ++i) v += agent_loadf(&part[(n1 * SPLIT + i) * 8 + tid]);
        sh.vsh[tid] = v;
    }
    __syncthreads();
    float n2 = 0.f;
#pragma unroll
    for (int s = 0; s < 8; ++s) { vp[s] = sh.vsh[s] * scale; n2 += vp[s] * vp[s]; }
    float f = (n2 / (1.f + n2)) * rsqrtf(n2 + 1e-8f);
#pragma unroll
    for (int s = 0; s < 8; ++s) vp[s] *= f;
    __syncthreads();   // vsh safe for reuse
}

// g for pair index i (bc = bc0+i), position slot j: gather from x (L1/L2-hot).
__device__ __forceinline__ float gather_g(const float* __restrict__ x, int b1, int bc,
                                          const int offhw[4], int j) {
    int b0 = bc >> 6, c = bc & 63;
    const float* xc = x + ((((b0 << 2) + b1) << 6) + c) * P_;
    return (offhw[j] >= 0) ? xc[offhw[j]] : 0.f;
}

// acc[s] += sum over owned elements of u_s * softmax_s(u*vp)  (log2e folded into wv)
__device__ __forceinline__ void route_acc(const float* __restrict__ x,
                                          const float* __restrict__ wgt,
                                          int b1, int k, int bc0, const int offhw[4],
                                          const float vp[8], float acc[8]) {
    for (int i = 0; i < BCPB; ++i) {
        int bc = bc0 + i;
        int c = bc & 63;
        const float* wc = wgt + c * (KLEN * S_) + k * S_;
        float w[8], wv[8];
#pragma unroll
        for (int s = 0; s < 8; ++s) { w[s] = wc[s]; wv[s] = w[s] * vp[s] * LOG2E; }
#pragma unroll
        for (int j = 0; j < 4; ++j) {
            float g = gather_g(x, b1, bc, offhw, j);
            // |g*w*vp| < ~0.5 -> softmax without max-subtraction is safe.
            float e[8]; float Z = 0.f;
#pragma unroll
            for (int s = 0; s < 8; ++s) { e[s] = __builtin_amdgcn_exp2f(g * wv[s]); Z += e[s]; }
            float sc = g * __builtin_amdgcn_rcpf(Z);   // u_s*c_s = (g*w_s)*(e_s/Z)
#pragma unroll
            for (int s = 0; s < 8; ++s) acc[s] += sc * w[s] * e[s];
        }
    }
}

__global__ void init_ctrl(unsigned* __restrict__ ctrl) {
    int t = threadIdx.x;
    if (t < NCTRL)
        __hip_atomic_store(&ctrl[t], 0u, __ATOMIC_RELAXED, __HIP_MEMORY_SCOPE_AGENT);
}

__global__ __launch_bounds__(THREADS, 4)   // VGPR<=128 -> >=4 blocks/CU -> 1024-block capacity
void cap_all(const float* __restrict__ x, const float* __restrict__ wgt,
             const int* __restrict__ indexm, float* __restrict__ ws,
             float* __restrict__ out)
{
    __shared__ SharedBufs sh;
    float* P1 = ws;
    float* P2 = ws + PBANK;
    float* P3 = ws + 2 * PBANK;
    unsigned* ctrl = (unsigned*)(ws + CTRL_OFF);
    unsigned* bar  = ctrl;          // [0],[1]: grid barriers
    unsigned* done = ctrl + 2;      // [n1]: pass-3 completion counters

    const int bid   = blockIdx.x;
    const int split = bid & (SPLIT - 1);
    const int n1    = bid >> 4;
    const int tid   = threadIdx.x;
    const int k = n1 % KLEN, b1 = n1 / KLEN;
    const int bc0 = split * BCPB;

    // Decode the 4 p-positions this thread owns into x-plane offsets (once).
    int offhw[4];
#pragma unroll
    for (int j = 0; j < 4; ++j) {
        int p = tid + j * THREADS;
        int idx = indexm[k * P_ + p];
        int r = idx / WP, cc = idx - r * WP;
        int ir = r - 1, ic = cc - 1;
        offhw[j] = (ir >= 0 && ir < HH && ic >= 0 && ic < WW) ? ir * WW + ic : -1;
    }

    // ---- pass 1: uniform-coupling sum (coupling 1/8 folded into pass-2 scale)
    {
        float acc[8] = {0.f,0.f,0.f,0.f,0.f,0.f,0.f,0.f};
        for (int i = 0; i < BCPB; ++i) {
            int bc = bc0 + i;
            int c = bc & 63;
            const float* wc = wgt + c * (KLEN * S_) + k * S_;
            float w[8];
#pragma unroll
            for (int s = 0; s < 8; ++s) w[s] = wc[s];
#pragma unroll
            for (int j = 0; j < 4; ++j) {
                float g = gather_g(x, b1, bc, offhw, j);
#pragma unroll
                for (int s = 0; s < 8; ++s) acc[s] += g * w[s];
            }
        }
        block_reduce_store(sh, acc, bid, P1);
    }
    grid_barrier(&bar[0]);

    // ---- pass 2
    {
        float vp[8];
        load_squash(sh, P1, n1, 0.125f, vp);
        float acc[8] = {0.f,0.f,0.f,0.f,0.f,0.f,0.f,0.f};
        route_acc(x, wgt, b1, k, bc0, offhw, vp, acc);
        block_reduce_store(sh, acc, bid, P2);
    }
    grid_barrier(&bar[1]);

    // ---- pass 3
    {
        float vp[8];
        load_squash(sh, P2, n1, 1.0f, vp);
        float acc[8] = {0.f,0.f,0.f,0.f,0.f,0.f,0.f,0.f};
        route_acc(x, wgt, b1, k, bc0, offhw, vp, acc);
        block_reduce_store(sh, acc, bid, P3);
    }

    // ---- finalize: last split-block of each n1 sums partials and writes out
    __syncthreads();   // drain this block's P3 stores (vmcnt 0 in every wave)
    if (tid == 0) {
        unsigned old = __hip_atomic_fetch_add(&done[n1], 1u, __ATOMIC_ACQ_REL,
                                              __HIP_MEMORY_SCOPE_AGENT);
        sh.last = (old == SPLIT - 1);
    }
    __syncthreads();
    if (sh.last) {
        if (tid < 8) {
            float v = 0.f;
#pragma unroll
            for (int i = 0; i < SPLIT; ++i)
                v += agent_loadf(&P3[(n1 * SPLIT + i) * 8 + tid]);
            sh.vsh[tid] = v;
        }
        __syncthreads();
        if (tid < 8) {
            float n2 = 0.f;
#pragma unroll
            for (int s = 0; s < 8; ++s) n2 += sh.vsh[s] * sh.vsh[s];
            float f = (n2 / (1.f + n2)) * rsqrtf(n2 + 1e-8f);
            out[n1 * 8 + tid] = sh.vsh[tid] * f * 0.5f + 0.5f;
        }
    }
}

extern "C" void kernel_launch(void* const* d_in, const int* in_sizes, int n_in,
                              void* d_out, int out_size, void* d_ws, size_t ws_size,
                              hipStream_t stream) {
    const float* x    = (const float*)d_in[0];
    const float* wgt  = (const float*)d_in[1];
    const int*   idxm = (const int*)d_in[2];
    float* ws = (float*)d_ws;
    unsigned* ctrl = (unsigned*)(ws + CTRL_OFF);

    init_ctrl<<<1, 64, 0, stream>>>(ctrl);
    cap_all<<<NBLK, THREADS, 0, stream>>>(x, wgt, idxm, ws, (float*)d_out);
}